// Round 14
// baseline (3220.613 us; speedup 1.0000x reference)
//
#include <hip/hip_runtime.h>
#include <stdint.h>

// GRU acoustic model, fp32 I/O. R21b: gi-hoist with a __device__ global
// buffer (R21's ws-guard tripped -- ws_size < 472MB -- so the gi path
// NEVER RAN; counters showed gru_enc_fb = R20 replay). Fix: gi lives in
// an uninitialized __device__ global (load-time allocation, SHT_NOBITS,
// no hipMalloc, graph-capture-safe); fallback deleted. Theory unchanged:
// gi[b][t][900] = x@Wih^T + ebih precomputed by a 256-CU memory-bound
// kernel (~80us, 472MB); the recurrence drops 3 MFBF + Ax ds_read + xt
// staging + x-prefetch machinery per step, loading 3 dwords/thread/step
// prefetched one full step ahead (lgkm-only barx -> loads float across
// barriers; slack ~2900cyc >> 900cyc HBM). Numerics: same quantities,
// fp-reassociation drift only. Decoder unchanged (R17 proven).
// Failure criterion: total >= 2600us -> revert to R20, declare plateau.
#define FEAT 13
#define EMB 300
#define BATCH 64
#define TSTEPS 2048
#define ROWS 4              // valid batch rows per WG
#define HSTR 320            // hbuf row stride, bytes (20 granules of 16)
#define QW  2199.7045f      // 127*sqrt(300)
#define SWH 3.5795795e-6f   // 1/(127*127*sqrt(300))
#define DEPS 1e-6f          // decoder convergence epsilon

typedef float  floatx4 __attribute__((ext_vector_type(4)));
typedef short  shortx8 __attribute__((ext_vector_type(8)));
typedef int    intx4   __attribute__((ext_vector_type(4)));

// gi buffer: 64*2048*900 f32 = 472MB, allocated at module load (.bss).
__device__ float gi_buf[(size_t)BATCH * TSTEPS * 900];

__device__ __forceinline__ float sigf(float x) {
  return __builtin_amdgcn_rcpf(1.f + __expf(-x));
}
__device__ __forceinline__ float tanhf_(float x) {
  return 1.f - 2.f * __builtin_amdgcn_rcpf(1.f + __expf(2.f * x));
}
__device__ __forceinline__ int q8w(float v) {
  return __float2int_rn(fminf(fmaxf(v * QW, -127.f), 127.f));
}
__device__ __forceinline__ float rdl(float v, int l) {
  union { float f; int i; } c; c.f = v;
  union { int i; float f; } o;
  o.i = __builtin_amdgcn_readlane(c.i, l);
  return o.f;
}

// Raw barrier: LDS-order only (no vmcnt drain; in-flight global loads
// float across it).
__device__ __forceinline__ void barx() {
  asm volatile("s_waitcnt lgkmcnt(0)" ::: "memory");
  __builtin_amdgcn_s_barrier();
  asm volatile("" ::: "memory");
}

#define MFI8(A, B, C) __builtin_amdgcn_mfma_i32_16x16x64_i8(A, B, C, 0, 0, 0)

// ---------------- gi precompute: gi[b][t][900] = x@Wih^T + ebih ------------
__launch_bounds__(256)
__global__ void gi_pre(const float* __restrict__ x,     // [64][2048][13]
                       const float* __restrict__ eWih,  // [900][13]
                       const float* __restrict__ ebih)  // [900]
{
  const int base = blockIdx.x * 8;
  for (int r = 0; r < 8; ++r) {
    const int bt = base + r;
    const float* xp = x + (size_t)bt * FEAT;
    float xv[FEAT];
#pragma unroll
    for (int f = 0; f < FEAT; ++f) xv[f] = xp[f];   // broadcast loads
    float* gp = gi_buf + (size_t)bt * 900;
    for (int c = threadIdx.x; c < 900; c += 256) {
      float a = ebih[c];
      const float* wr = eWih + c * FEAT;
#pragma unroll
      for (int f = 0; f < FEAT; ++f) a = fmaf(xv[f], wr[f], a);
      gp[c] = a;                                     // coalesced
    }
  }
}

// ---------------- encoder (gi-fed): no per-step Wih*x ----------------------
__launch_bounds__(1024, 4)
__global__ void gru_enc(const float* __restrict__ eWhh, // [900][300]
                        const float* __restrict__ ebhh, // [900]
                        const float* __restrict__ fcW,  // [300][300]
                        const float* __restrict__ fcb,  // [300]
                        float* __restrict__ out) {
  // hb: element (row r, col c) at byte r*HSTR + (c ^ (r<<4)); for
  // c = kt*64 + q*16 + nl this flattens to r*HSTR + ((q^r)<<4) + kt*64.
  __shared__ __align__(16) signed char hb[2][ROWS][HSTR];     // 2560 B
  __shared__ __align__(16) signed char zpad[HSTR];            // zero region
  __shared__ __align__(16) signed char wl4[16][3][1024];      // 49152 B
  __shared__ __align__(16) signed char wlB[3][3][5][1024];    // 46080 B
  __shared__ __align__(16) floatx4     ebE[3][16];            // 768 B

  const int tid = threadIdx.x, lane = tid & 63, w = tid >> 6;   // w in [0,16)
  const int nl = lane & 15, q = lane >> 4;
  const int g = blockIdx.x;          // batch rows 4g..4g+3

  // ---- preamble: own slice w -> regs (kt 0-3) + wl4 (kt 4) ----
  intx4 Bh[3][4];
  float bhhR, bhhZ, bHN;
  {
    const int jj = 16 * w + nl;            // <= 255+15 < EMB: always valid
#pragma unroll
    for (int gt = 0; gt < 3; ++gt) {
      const int R = gt * EMB + jj;
      for (int kt = 0; kt < 5; ++kt) {
        int bb[4] = {0, 0, 0, 0};
        for (int e = 0; e < 16; ++e) {
          int kk = kt * 64 + q * 16 + e;
          float v = (kk < EMB) ? eWhh[(size_t)R * EMB + kk] : 0.f;
          bb[e >> 2] |= (q8w(v) & 255) << ((e & 3) * 8);
        }
        intx4 t4; t4[0] = bb[0]; t4[1] = bb[1]; t4[2] = bb[2]; t4[3] = bb[3];
        if (kt < 4) Bh[gt][kt] = t4;
        else        *(intx4*)&wl4[w][gt][lane * 16] = t4;
      }
    }
    bhhR = ebhh[jj];
    bhhZ = ebhh[EMB + jj];
    bHN  = ebhh[2 * EMB + jj];
  }
  // ---- extra slices 16-18: Whh blocks filled by waves 7-15 ----
  if (w >= 7) {
    const int u = w - 7, eI = u / 3, gt = u - 3 * eI;
    const int jj = 16 * (16 + eI) + nl;
    const bool jvv = (jj < EMB);
    const int R = gt * EMB + (jvv ? jj : 0);
    for (int kt = 0; kt < 5; ++kt) {
      int bb[4] = {0, 0, 0, 0};
      for (int e = 0; e < 16; ++e) {
        int kk = kt * 64 + q * 16 + e;
        float v = (jvv && kk < EMB) ? eWhh[(size_t)R * EMB + kk] : 0.f;
        bb[e >> 2] |= (q8w(v) & 255) << ((e & 3) * 8);
      }
      intx4 t4; t4[0] = bb[0]; t4[1] = bb[1]; t4[2] = bb[2]; t4[3] = bb[3];
      *(intx4*)&wlB[eI][gt][kt][lane * 16] = t4;
    }
  }
  // ---- extra slices' biases + valid mask (wave 6) ----
  if (w == 6 && lane < 48) {
    const int eI = lane >> 4, j2 = lane & 15;
    const int jj = 16 * (16 + eI) + j2;
    const bool jvv = (jj < EMB);
    floatx4 v;
    v[0] = jvv ? ebhh[jj] : 0.f;
    v[1] = jvv ? ebhh[EMB + jj] : 0.f;
    v[2] = jvv ? ebhh[2 * EMB + jj] : 0.f;
    v[3] = jvv ? 1.f : 0.f;              // valid-lane mask for gi
    ebE[eI][j2] = v;
  }

  // ---- init LDS: zero h buffers + zero pad ----
  for (int i = tid; i < 2 * ROWS * HSTR; i += 1024) ((signed char*)hb)[i] = 0;
  for (int i = tid; i < HSTR; i += 1024) zpad[i] = 0;
  __syncthreads();

  // ---- hoisted loop-invariant addressing ----
  const int rr_ = nl >> 2;               // A-side batch row (if nl%4==0)
  const bool areal = ((nl & 3) == 0);
  const signed char* aRead =
      areal ? (&hb[0][0][0] + rr_ * HSTR + ((q ^ rr_) << 4)) : zpad;
  int dA = areal ? (ROWS * HSTR) : 0;
  const int cown = 16 * w + nl;
  signed char* hw = &hb[1][q][0] + (cown ^ (q << 4));   // t=1 writes hb[1]
  const int cext = 16 * (16 + (w < 3 ? w : 0)) + nl;
  signed char* hwE = &hb[1][q][0] + (cext ^ (q << 4));
  int dH = -(ROWS * HSTR);
  const signed char* wb4 = &wl4[w][0][lane * 16];        // gt stride 1024B
  const signed char* wbB = &wlB[w < 3 ? w : 0][0][0][lane * 16];
  floatx4 ebv = {0.f, 0.f, 0.f, 0.f};
  if (w < 3) ebv = ebE[w][nl];

  // ---- gi prefetch pipeline (own: every thread; extra: waves 0-2) ----
  const size_t gbase = (size_t)(g * ROWS + q) * TSTEPS * 900;
  const float* gp = gi_buf + gbase + (16 * w + nl);
  float gR = gp[0], gZ = gp[300], gN = gp[600];   // step 1 consumes row 0
  gp += 900;
  const int jjE = 16 * (16 + (w < 3 ? w : 0)) + nl;
  const float* gpe = gi_buf + gbase + (jjE < EMB ? jjE : 0);
  float gRE = 0.f, gZE = 0.f, gNE = 0.f;
  if (w < 3) { gRE = gpe[0]; gZE = gpe[300]; gNE = gpe[600]; }
  gpe += 900;

  float hprev = 0.f, hpE = 0.f;

  // ================= recurrence: ONE lgkm barrier/step =================
  for (int t = 1; t <= TSTEPS; ++t) {
    // prefetch next step's gi (consumed next iter; in flight across barx)
    float gRn = 0.f, gZn = 0.f, gNn = 0.f;
    if (t < TSTEPS) { gRn = gp[0]; gZn = gp[300]; gNn = gp[600]; gp += 900; }
    float gREn = 0.f, gZEn = 0.f, gNEn = 0.f;
    if (w < 3 && t < TSTEPS) {
      gREn = gpe[0]; gZEn = gpe[300]; gNEn = gpe[600]; gpe += 900;
    }

    intx4 Ah[5];
#pragma unroll
    for (int kt = 0; kt < 5; ++kt)
      Ah[kt] = *(const intx4*)(aRead + kt * 64);

    // own slice: 15 MFI8 (kt<4 reg-B, kt=4 LDS-B)
    intx4 aR = {0, 0, 0, 0}, aZ = {0, 0, 0, 0}, aN = {0, 0, 0, 0};
#pragma unroll
    for (int kt = 0; kt < 4; ++kt) {
      aR = MFI8(Ah[kt], Bh[0][kt], aR);
      aZ = MFI8(Ah[kt], Bh[1][kt], aZ);
      aN = MFI8(Ah[kt], Bh[2][kt], aN);
    }
    aR = MFI8(Ah[4], *(const intx4*)(wb4), aR);
    aZ = MFI8(Ah[4], *(const intx4*)(wb4 + 1024), aZ);
    aN = MFI8(Ah[4], *(const intx4*)(wb4 + 2048), aN);
    {
      // reg 0 = (batch row q, col 16w+nl) — gates fully in-register
      float r  = sigf((float)aR[0] * SWH + gR + bhhR);
      float z  = sigf((float)aZ[0] * SWH + gZ + bhhZ);
      float hn = (float)aN[0] * SWH + bHN;
      float n  = tanhf_(gN + r * hn);
      float h  = z * (hprev - n) + n;
      hprev = h;
      float hq = fminf(fmaxf(h * 127.f, -127.f), 127.f);
      *hw = (signed char)__float2int_rn(hq);
    }
    if (w < 3) {   // extra slice 16+w: reuse Ah regs, B from LDS
      intx4 aR2 = {0, 0, 0, 0}, aZ2 = {0, 0, 0, 0}, aN2 = {0, 0, 0, 0};
#pragma unroll
      for (int kt = 0; kt < 5; ++kt) {
        aR2 = MFI8(Ah[kt], *(const intx4*)(wbB + kt * 1024), aR2);
        aZ2 = MFI8(Ah[kt], *(const intx4*)(wbB + 5120 + kt * 1024), aZ2);
        aN2 = MFI8(Ah[kt], *(const intx4*)(wbB + 10240 + kt * 1024), aN2);
      }
      const float jm = ebv[3];           // 0 for cols >= 300 -> h stays 0
      float r  = sigf((float)aR2[0] * SWH + gRE * jm + ebv[0]);
      float z  = sigf((float)aZ2[0] * SWH + gZE * jm + ebv[1]);
      float hn = (float)aN2[0] * SWH + ebv[2];
      float n  = tanhf_(gNE * jm + r * hn);
      float h  = z * (hpE - n) + n;
      hpE = h;
      float hq = fminf(fmaxf(h * 127.f, -127.f), 127.f);
      *hwE = (signed char)__float2int_rn(hq);
    }

    // phase-pointer maintenance
    aRead += dA; dA = -dA;
    hw += dH;    hwE += dH;  dH = -dH;

    barx();   // h_t visible; hb double-buffered
    gR = gRn; gZ = gZn; gN = gNn;
    gRE = gREn; gZE = gZEn; gNE = gNEn;
  }

  // ================= fc: emb = relu(h_T @ fcW^T + fcb) =================
  {
    float* oemb = out + (size_t)BATCH * TSTEPS * FEAT;
    const signed char* aT =
        areal ? (&hb[0][0][0] + rr_ * HSTR + ((q ^ rr_) << 4)) : zpad;
    intx4 AhT[5];
#pragma unroll
    for (int kt = 0; kt < 5; ++kt)   // T even -> final h in hb[0]
      AhT[kt] = *(const intx4*)(aT + kt * 64);
#pragma unroll
    for (int u = 0; u < 2; ++u) {
      const int s = w + 16 * u;
      if (s < 19) {   // wave-uniform
        const int jj = 16 * s + nl;
        const bool jvv = (jj < EMB);
        intx4 acc = {0, 0, 0, 0};
        for (int kt = 0; kt < 5; ++kt) {
          int bb[4] = {0, 0, 0, 0};
          for (int e = 0; e < 16; ++e) {
            int kk = kt * 64 + q * 16 + e;
            float v = (jvv && kk < EMB) ? fcW[(size_t)jj * EMB + kk] : 0.f;
            bb[e >> 2] |= (q8w(v) & 255) << ((e & 3) * 8);
          }
          intx4 b4; b4[0] = bb[0]; b4[1] = bb[1]; b4[2] = bb[2]; b4[3] = bb[3];
          acc = MFI8(AhT[kt], b4, acc);
        }
        if (jvv) {  // reg 0 = (batch row q, col jj)
          float e2 = (float)acc[0] * SWH + fcb[jj];
          oemb[(size_t)(g * ROWS + q) * EMB + jj] = e2 > 0.f ? e2 : 0.f;
        }
      }
    }
  }
}

// ---------------- decoder: 1 wave per batch, all fp32 ----------------------
// R17 (proven): epsilon-convergence stop; readlane broadcast; lane-local
// ILP-3 gates; coalesced constant tail-fill. Unchanged.
__launch_bounds__(64, 1)
__global__ void gru_dec(const float* __restrict__ dWih,  // [39][300]
                        const float* __restrict__ dWhh,  // [39][13]
                        const float* __restrict__ dbih,  // [39]
                        const float* __restrict__ dbhh,  // [39]
                        float* __restrict__ out) {
  __shared__ float hsh[FEAT];
  const int b = blockIdx.x;
  const int j = threadIdx.x;             // lane; j<13 owns h[j]
  const bool own = (j < FEAT);
  const float* emb = out + (size_t)BATCH * TSTEPS * FEAT + (size_t)b * EMB;

  float gi = 0.f;
  if (j < 3 * FEAT) {
    gi = dbih[j];
#pragma unroll 4
    for (int k = 0; k < EMB; ++k)
      gi = fmaf(emb[k], dWih[j * EMB + k], gi);
  }
  const float gir = __shfl(gi, j);
  const float giz = __shfl(gi, FEAT + j);
  const float gin = __shfl(gi, 2 * FEAT + j);

  float Wr[FEAT], Wz[FEAT], Wn[FEAT];
#pragma unroll
  for (int k = 0; k < FEAT; ++k) { Wr[k] = 0.f; Wz[k] = 0.f; Wn[k] = 0.f; }
  float br = 0.f, bz = 0.f, bn = 0.f;
  if (own) {
#pragma unroll
    for (int k = 0; k < FEAT; ++k) {
      Wr[k] = dWhh[j * FEAT + k];
      Wz[k] = dWhh[(FEAT + j) * FEAT + k];
      Wn[k] = dWhh[(2 * FEAT + j) * FEAT + k];
    }
    br = dbhh[j]; bz = dbhh[FEAT + j]; bn = dbhh[2 * FEAT + j];
  }

  float hown = 0.f;
  float* orow = out + (size_t)b * TSTEPS * FEAT;

  for (int t = 0; t < TSTEPS; ++t) {
    float hs[FEAT];
#pragma unroll
    for (int k = 0; k < FEAT; ++k) hs[k] = rdl(hown, k);   // SGPR broadcast
    float ghr = br, ghz = bz, ghn = bn;   // 3 independent chains (ILP 3)
#pragma unroll
    for (int k = 0; k < FEAT; ++k) {
      ghr = fmaf(Wr[k], hs[k], ghr);
      ghz = fmaf(Wz[k], hs[k], ghz);
      ghn = fmaf(Wn[k], hs[k], ghn);
    }
    float r  = sigf(gir + ghr);
    float z  = sigf(giz + ghz);
    float nn = tanhf_(gin + r * ghn);
    float hn = z * (hown - nn) + nn;
    bool conv = (!own) || (fabsf(hn - hown) <= DEPS);
    if (own) {
      orow[t * FEAT + j] = hn;           // lanes 0-12: contiguous 52B
      hown = hn;
    }
    if (__all(conv)) {  // converged within eps -> tail is ~constant
      if (own) hsh[j] = hown;
      asm volatile("s_waitcnt lgkmcnt(0)" ::: "memory");
      const int total = TSTEPS * FEAT;
      int idx = (t + 1) * FEAT + j;
      if (idx < total) {
        int jj = idx % FEAT;             // one div at entry
        for (; idx < total; idx += 64) {
          orow[idx] = hsh[jj];           // 64x4B coalesced per iteration
          jj = (jj == 0) ? (FEAT - 1) : (jj - 1);   // (jj+64) mod 13
        }
      }
      break;
    }
  }
}

extern "C" void kernel_launch(void* const* d_in, const int* in_sizes, int n_in,
                              void* d_out, int out_size, void* d_ws, size_t ws_size,
                              hipStream_t stream) {
  (void)in_sizes; (void)n_in; (void)out_size; (void)d_ws; (void)ws_size;
  const float* x    = (const float*)d_in[0];
  const float* eWih = (const float*)d_in[1];
  const float* eWhh = (const float*)d_in[2];
  const float* ebih = (const float*)d_in[3];
  const float* ebhh = (const float*)d_in[4];
  const float* fcW  = (const float*)d_in[5];
  const float* fcb  = (const float*)d_in[6];
  const float* dWih = (const float*)d_in[7];
  const float* dWhh = (const float*)d_in[8];
  const float* dbih = (const float*)d_in[9];
  const float* dbhh = (const float*)d_in[10];

  hipLaunchKernelGGL(gi_pre, dim3(BATCH * TSTEPS / 8), dim3(256), 0, stream,
                     x, eWih, ebih);
  hipLaunchKernelGGL(gru_enc, dim3(BATCH / ROWS), dim3(1024), 0, stream,
                     eWhh, ebhh, fcW, fcb, (float*)d_out);
  hipLaunchKernelGGL(gru_dec, dim3(BATCH), dim3(64), 0, stream,
                     dWih, dWhh, dbih, dbhh, (float*)d_out);
}

// Round 15
// 2538.935 us; speedup vs baseline: 1.2685x; 1.2685x over previous
//
#include <hip/hip_runtime.h>
#include <stdint.h>

// GRU acoustic model, fp32 I/O. R22: final revert to R20/R18 (best proven:
// 2548us total; enc ~2458 x4 confirmations, dec ~90). R21b post-mortem:
// gi-hoist RAN (FETCH 240MB, absmax 0.0078) and was SLOWER (enc ~2790,
// total 3221): the per-step Wih*x (3 MFBF + 1 ds_read) was effectively
// free (overlapped the MFI8 stream + gave the scheduler filler), while
// 3 HBM-streaming loads/thread/step put cold-miss latency INSIDE the
// serial loop (MfmaUtil 2.96->2.16). Lesson: in a latency-bound serial
// recurrence, compute-from-resident beats streamed-precompute even at a
// 20x FLOP disadvantage. Session: 4358 -> 2548us (-42%). 10 isolated
// perturbations tested; every neighbor of this structure is slower.
// Enc: R12 loop + phase pointers (ptr+=d; d=-d) + hoisted weight-LDS
// bases + extra-slice A-reg reuse. Dec: R17 epsilon stop + readlane
// broadcast + coalesced tail-fill.
#define FEAT 13
#define EMB 300
#define BATCH 64
#define TSTEPS 2048
#define ROWS 4              // valid batch rows per WG
#define HSTR 320            // hbuf row stride, bytes (20 granules of 16)
#define QW  2199.7045f      // 127*sqrt(300)
#define SWH 3.5795795e-6f   // 1/(127*127*sqrt(300))
#define DEPS 1e-6f          // decoder convergence epsilon

typedef float  floatx4 __attribute__((ext_vector_type(4)));
typedef short  shortx8 __attribute__((ext_vector_type(8)));
typedef int    intx4   __attribute__((ext_vector_type(4)));

__device__ __forceinline__ uint16_t f2b(float f) {
  union { float f; uint32_t i; } c; c.f = f;
  uint32_t r = c.i + 0x7fffu + ((c.i >> 16) & 1u);
  return (uint16_t)(r >> 16);
}
__device__ __forceinline__ float sigf(float x) {
  return __builtin_amdgcn_rcpf(1.f + __expf(-x));
}
__device__ __forceinline__ float tanhf_(float x) {
  return 1.f - 2.f * __builtin_amdgcn_rcpf(1.f + __expf(2.f * x));
}
__device__ __forceinline__ int q8w(float v) {
  return __float2int_rn(fminf(fmaxf(v * QW, -127.f), 127.f));
}
__device__ __forceinline__ float rdl(float v, int l) {
  union { float f; int i; } c; c.f = v;
  union { int i; float f; } o;
  o.i = __builtin_amdgcn_readlane(c.i, l);
  return o.f;
}

// Raw barrier: LDS-order only (no vmcnt drain; wave 15's global x loads
// stay in flight across it).
__device__ __forceinline__ void barx() {
  asm volatile("s_waitcnt lgkmcnt(0)" ::: "memory");
  __builtin_amdgcn_s_barrier();
  asm volatile("" ::: "memory");
}

#define MFI8(A, B, C) __builtin_amdgcn_mfma_i32_16x16x64_i8(A, B, C, 0, 0, 0)
#define MFBF(A, B, C) __builtin_amdgcn_mfma_f32_16x16x32_bf16(A, B, C, 0, 0, 0)

__launch_bounds__(1024, 4)
__global__ void gru_enc(const float* __restrict__ x,     // [64][2048][13]
                        const float* __restrict__ eWih,  // [900][13]
                        const float* __restrict__ eWhh,  // [900][300]
                        const float* __restrict__ ebih,  // [900]
                        const float* __restrict__ ebhh,  // [900]
                        const float* __restrict__ fcW,   // [300][300]
                        const float* __restrict__ fcb,   // [300]
                        float* __restrict__ out) {
  // hb: element (row r, col c) at byte r*HSTR + (c ^ (r<<4)); for
  // c = kt*64 + q*16 + nl this flattens to r*HSTR + ((q^r)<<4) + kt*64.
  // Logical pad granule 19 maps to the per-row never-written physical
  // granule -> reads return 0.
  __shared__ __align__(16) signed char hb[2][ROWS][HSTR];     // 2560 B
  __shared__ __align__(16) signed char zpad[HSTR];            // zero region
  __shared__ __align__(16) uint16_t    xt[2][16][32];         // 2048 B
  __shared__ __align__(16) signed char wl4[16][3][1024];      // 49152 B
  __shared__ __align__(16) signed char wlB[3][3][5][1024];    // 46080 B
  __shared__ __align__(16) uint16_t    wxE[3][3][64][8];      // 9216 B
  __shared__ __align__(16) floatx4     ebE[3][16];            // 768 B

  const int tid = threadIdx.x, lane = tid & 63, w = tid >> 6;   // w in [0,16)
  const int nl = lane & 15, q = lane >> 4;
  const int g = blockIdx.x;          // batch rows 4g..4g+3

  // ---- preamble: own slice w -> regs (kt 0-3) + wl4 (kt 4) ----
  intx4   Bh[3][4];
  shortx8 Bx[3];
  float bS0, bS1, bHN, bIN;
  {
    const int jj = 16 * w + nl;            // <= 255+15 < EMB: always valid
#pragma unroll
    for (int gt = 0; gt < 3; ++gt) {
      const int R = gt * EMB + jj;
      for (int kt = 0; kt < 5; ++kt) {
        int bb[4] = {0, 0, 0, 0};
        for (int e = 0; e < 16; ++e) {
          int kk = kt * 64 + q * 16 + e;
          float v = (kk < EMB) ? eWhh[(size_t)R * EMB + kk] : 0.f;
          bb[e >> 2] |= (q8w(v) & 255) << ((e & 3) * 8);
        }
        intx4 t4; t4[0] = bb[0]; t4[1] = bb[1]; t4[2] = bb[2]; t4[3] = bb[3];
        if (kt < 4) Bh[gt][kt] = t4;
        else        *(intx4*)&wl4[w][gt][lane * 16] = t4;
      }
      union { uint16_t u[8]; shortx8 v; } c;
      for (int e = 0; e < 8; ++e) {
        int kk = q * 8 + e;
        c.u[e] = (kk < FEAT) ? f2b(eWih[R * FEAT + kk]) : (uint16_t)0;
      }
      Bx[gt] = c.v;
    }
    bS0 = ebih[jj] + ebhh[jj];
    bS1 = ebih[EMB + jj] + ebhh[EMB + jj];
    bHN = ebhh[2 * EMB + jj];
    bIN = ebih[2 * EMB + jj];
  }
  // ---- extra slices 16-18: Whh blocks filled by waves 7-15 ----
  if (w >= 7) {
    const int u = w - 7, eI = u / 3, gt = u - 3 * eI;
    const int jj = 16 * (16 + eI) + nl;
    const bool jvv = (jj < EMB);
    const int R = gt * EMB + (jvv ? jj : 0);
    for (int kt = 0; kt < 5; ++kt) {
      int bb[4] = {0, 0, 0, 0};
      for (int e = 0; e < 16; ++e) {
        int kk = kt * 64 + q * 16 + e;
        float v = (jvv && kk < EMB) ? eWhh[(size_t)R * EMB + kk] : 0.f;
        bb[e >> 2] |= (q8w(v) & 255) << ((e & 3) * 8);
      }
      intx4 t4; t4[0] = bb[0]; t4[1] = bb[1]; t4[2] = bb[2]; t4[3] = bb[3];
      *(intx4*)&wlB[eI][gt][kt][lane * 16] = t4;
    }
  }
  // ---- extra slices' Wih fragments (waves 3-5) ----
  if (w >= 3 && w < 6) {
    const int eI = w - 3;
    const int jj = 16 * (16 + eI) + nl;
    const bool jvv = (jj < EMB);
    const int R0 = jvv ? jj : 0;
#pragma unroll
    for (int gt = 0; gt < 3; ++gt) {
      union { uint16_t u[8]; shortx8 v; } c;
      for (int e = 0; e < 8; ++e) {
        int kk = q * 8 + e;
        c.u[e] = (jvv && kk < FEAT)
                     ? f2b(eWih[(size_t)(gt * EMB + R0) * FEAT + kk])
                     : (uint16_t)0;
      }
      *(shortx8*)&wxE[eI][gt][lane][0] = c.v;
    }
  }
  // ---- extra slices' biases (wave 6) ----
  if (w == 6 && lane < 48) {
    const int eI = lane >> 4, j2 = lane & 15;
    const int jj = 16 * (16 + eI) + j2;
    const bool jvv = (jj < EMB);
    floatx4 v;
    v[0] = jvv ? (ebih[jj] + ebhh[jj]) : 0.f;
    v[1] = jvv ? (ebih[EMB + jj] + ebhh[EMB + jj]) : 0.f;
    v[2] = jvv ? ebhh[2 * EMB + jj] : 0.f;
    v[3] = jvv ? ebih[2 * EMB + jj] : 0.f;
    ebE[eI][j2] = v;
  }

  // ---- init LDS: zero h/x buffers + zero pad, then stage x_0 ----
  for (int i = tid; i < 2 * ROWS * HSTR; i += 1024) ((signed char*)hb)[i] = 0;
  for (int i = tid; i < HSTR; i += 1024) zpad[i] = 0;
  for (int i = tid; i < 2 * 16 * 32; i += 1024) ((uint16_t*)xt)[i] = 0;
  __syncthreads();
  if (tid < ROWS * FEAT) {
    int m = tid / FEAT, f = tid - m * FEAT;
    xt[0][4 * m][f] = f2b(x[((size_t)(g * ROWS + m) * TSTEPS) * FEAT + f]);
  }
  __syncthreads();

  // ---- hoisted loop-invariant addressing ----
  const int rr_ = nl >> 2;               // A-side batch row (if nl%4==0)
  const bool areal = ((nl & 3) == 0);
  // A-read base: phase-alternating via aRead += dA; dA = -dA (zero lanes
  // stay inside zpad with dA=0; kt offsets are immediates 0..256).
  const signed char* aRead =
      areal ? (&hb[0][0][0] + rr_ * HSTR + ((q ^ rr_) << 4)) : zpad;
  int dA = areal ? (ROWS * HSTR) : 0;
  const uint16_t* xr = &xt[0][nl][q * 8];
  int dX = 16 * 32;                      // u16 elements per phase
  const int cown = 16 * w + nl;
  signed char* hw = &hb[1][q][0] + (cown ^ (q << 4));   // t=1 writes hb[1]
  const int cext = 16 * (16 + (w < 3 ? w : 0)) + nl;
  signed char* hwE = &hb[1][q][0] + (cext ^ (q << 4));
  int dH = -(ROWS * HSTR);
  const signed char* wb4 = &wl4[w][0][lane * 16];        // gt stride 1024B
  const signed char* wbB = &wlB[w < 3 ? w : 0][0][0][lane * 16];
  const uint16_t*    wxb = &wxE[w < 3 ? w : 0][0][lane][0]; // gt stride 512
  floatx4 ebv = {0.f, 0.f, 0.f, 0.f};
  if (w < 3) ebv = ebE[w][nl];
  const floatx4 zf = {0.f, 0.f, 0.f, 0.f};

  // ---- x prefetch pipeline (wave 15, SIMD3) ----
  const bool xl = (w == 15) && (lane < ROWS * FEAT);
  const int xm = lane / FEAT, xf = lane - xm * FEAT;
  const float* xbase = x + ((size_t)(g * ROWS + xm) * TSTEPS) * FEAT + xf;
  float xcur = 0.f;                      // x_t, staged bottom of iter t
  if (xl) xcur = xbase[FEAT];            // x_1
  const float* xnq = xbase + 2 * FEAT;   // next load: x_2
  uint16_t* xw = &xt[1][4 * xm][xf];     // t=1 writes xt[1]
  int dXW = -(16 * 32);

  float hprev = 0.f, hpE = 0.f;

  // ================= recurrence: ONE lgkm barrier/step =================
  for (int t = 1; t <= TSTEPS; ++t) {
    float xnxt = 0.f;
    if (xl && t < TSTEPS - 1) { xnxt = *xnq; xnq += FEAT; }

    intx4 Ah[5];
#pragma unroll
    for (int kt = 0; kt < 5; ++kt)
      Ah[kt] = *(const intx4*)(aRead + kt * 64);
    const shortx8 Ax = *(const shortx8*)xr;

    // own slice: 15 MFI8 (kt<4 reg-B, kt=4 LDS-B) + 3 MFBF
    intx4 aR = {0, 0, 0, 0}, aZ = {0, 0, 0, 0}, aN = {0, 0, 0, 0};
#pragma unroll
    for (int kt = 0; kt < 4; ++kt) {
      aR = MFI8(Ah[kt], Bh[0][kt], aR);
      aZ = MFI8(Ah[kt], Bh[1][kt], aZ);
      aN = MFI8(Ah[kt], Bh[2][kt], aN);
    }
    aR = MFI8(Ah[4], *(const intx4*)(wb4), aR);
    aZ = MFI8(Ah[4], *(const intx4*)(wb4 + 1024), aZ);
    aN = MFI8(Ah[4], *(const intx4*)(wb4 + 2048), aN);
    {
      floatx4 xR = MFBF(Ax, Bx[0], zf);
      floatx4 xZ = MFBF(Ax, Bx[1], zf);
      floatx4 xN = MFBF(Ax, Bx[2], zf);
      // reg 0 = (batch row q, col 16w+nl) — gates fully in-register
      float r  = sigf((float)aR[0] * SWH + xR[0] + bS0);
      float z  = sigf((float)aZ[0] * SWH + xZ[0] + bS1);
      float hn = (float)aN[0] * SWH + bHN;
      float n  = tanhf_(xN[0] + bIN + r * hn);
      float h  = z * (hprev - n) + n;
      hprev = h;
      float hq = fminf(fmaxf(h * 127.f, -127.f), 127.f);
      *hw = (signed char)__float2int_rn(hq);
    }
    if (w < 3) {   // extra slice 16+w: reuse Ah regs, B from LDS
      intx4 aR2 = {0, 0, 0, 0}, aZ2 = {0, 0, 0, 0}, aN2 = {0, 0, 0, 0};
#pragma unroll
      for (int kt = 0; kt < 5; ++kt) {
        aR2 = MFI8(Ah[kt], *(const intx4*)(wbB + kt * 1024), aR2);
        aZ2 = MFI8(Ah[kt], *(const intx4*)(wbB + 5120 + kt * 1024), aZ2);
        aN2 = MFI8(Ah[kt], *(const intx4*)(wbB + 10240 + kt * 1024), aN2);
      }
      floatx4 xR = MFBF(Ax, *(const shortx8*)(wxb), zf);
      floatx4 xZ = MFBF(Ax, *(const shortx8*)(wxb + 512), zf);
      floatx4 xN = MFBF(Ax, *(const shortx8*)(wxb + 1024), zf);
      float r  = sigf((float)aR2[0] * SWH + xR[0] + ebv[0]);
      float z  = sigf((float)aZ2[0] * SWH + xZ[0] + ebv[1]);
      float hn = (float)aN2[0] * SWH + ebv[2];
      float n  = tanhf_(xN[0] + ebv[3] + r * hn);
      float h  = z * (hpE - n) + n;
      hpE = h;
      float hq = fminf(fmaxf(h * 127.f, -127.f), 127.f);
      *hwE = (signed char)__float2int_rn(hq);
    }
    // wave 15: stage x_t (loaded last iter -> a full step of vmcnt slack)
    if (xl && t < TSTEPS) *xw = f2b(xcur);

    // phase-pointer maintenance (2 VALU ops each, replaces recompute)
    aRead += dA; dA = -dA;
    xr += dX;    dX = -dX;
    hw += dH;    hwE += dH;  dH = -dH;
    xw += dXW;   dXW = -dXW;

    barx();   // h_t + x_t visible; hb double-buffered
    xcur = xnxt;
  }

  // ================= fc: emb = relu(h_T @ fcW^T + fcb) =================
  {
    float* oemb = out + (size_t)BATCH * TSTEPS * FEAT;
    const signed char* aT =
        areal ? (&hb[0][0][0] + rr_ * HSTR + ((q ^ rr_) << 4)) : zpad;
    intx4 AhT[5];
#pragma unroll
    for (int kt = 0; kt < 5; ++kt)   // T even -> final h in hb[0]
      AhT[kt] = *(const intx4*)(aT + kt * 64);
#pragma unroll
    for (int u = 0; u < 2; ++u) {
      const int s = w + 16 * u;
      if (s < 19) {   // wave-uniform
        const int jj = 16 * s + nl;
        const bool jvv = (jj < EMB);
        intx4 acc = {0, 0, 0, 0};
        for (int kt = 0; kt < 5; ++kt) {
          int bb[4] = {0, 0, 0, 0};
          for (int e = 0; e < 16; ++e) {
            int kk = kt * 64 + q * 16 + e;
            float v = (jvv && kk < EMB) ? fcW[(size_t)jj * EMB + kk] : 0.f;
            bb[e >> 2] |= (q8w(v) & 255) << ((e & 3) * 8);
          }
          intx4 b4; b4[0] = bb[0]; b4[1] = bb[1]; b4[2] = bb[2]; b4[3] = bb[3];
          acc = MFI8(AhT[kt], b4, acc);
        }
        if (jvv) {  // reg 0 = (batch row q, col jj)
          float e2 = (float)acc[0] * SWH + fcb[jj];
          oemb[(size_t)(g * ROWS + q) * EMB + jj] = e2 > 0.f ? e2 : 0.f;
        }
      }
    }
  }
}

// ---------------- decoder: 1 wave per batch, all fp32 ----------------------
// R17 (proven): epsilon-convergence stop (|hn-hown| <= 1e-6 on owner
// lanes); readlane broadcast, lane-local ILP-3 gates, coalesced constant
// tail-fill. Unchanged.
__launch_bounds__(64, 1)
__global__ void gru_dec(const float* __restrict__ dWih,  // [39][300]
                        const float* __restrict__ dWhh,  // [39][13]
                        const float* __restrict__ dbih,  // [39]
                        const float* __restrict__ dbhh,  // [39]
                        float* __restrict__ out) {
  __shared__ float hsh[FEAT];
  const int b = blockIdx.x;
  const int j = threadIdx.x;             // lane; j<13 owns h[j]
  const bool own = (j < FEAT);
  const float* emb = out + (size_t)BATCH * TSTEPS * FEAT + (size_t)b * EMB;

  // one-time: gi for gate-row j on lanes 0-38
  float gi = 0.f;
  if (j < 3 * FEAT) {
    gi = dbih[j];
#pragma unroll 4
    for (int k = 0; k < EMB; ++k)
      gi = fmaf(emb[k], dWih[j * EMB + k], gi);
  }
  const float gir = __shfl(gi, j);
  const float giz = __shfl(gi, FEAT + j);
  const float gin = __shfl(gi, 2 * FEAT + j);

  float Wr[FEAT], Wz[FEAT], Wn[FEAT];
#pragma unroll
  for (int k = 0; k < FEAT; ++k) { Wr[k] = 0.f; Wz[k] = 0.f; Wn[k] = 0.f; }
  float br = 0.f, bz = 0.f, bn = 0.f;
  if (own) {
#pragma unroll
    for (int k = 0; k < FEAT; ++k) {
      Wr[k] = dWhh[j * FEAT + k];
      Wz[k] = dWhh[(FEAT + j) * FEAT + k];
      Wn[k] = dWhh[(2 * FEAT + j) * FEAT + k];
    }
    br = dbhh[j]; bz = dbhh[FEAT + j]; bn = dbhh[2 * FEAT + j];
  }

  float hown = 0.f;
  float* orow = out + (size_t)b * TSTEPS * FEAT;

  for (int t = 0; t < TSTEPS; ++t) {
    float hs[FEAT];
#pragma unroll
    for (int k = 0; k < FEAT; ++k) hs[k] = rdl(hown, k);   // SGPR broadcast
    float ghr = br, ghz = bz, ghn = bn;   // 3 independent chains (ILP 3)
#pragma unroll
    for (int k = 0; k < FEAT; ++k) {
      ghr = fmaf(Wr[k], hs[k], ghr);
      ghz = fmaf(Wz[k], hs[k], ghz);
      ghn = fmaf(Wn[k], hs[k], ghn);
    }
    float r  = sigf(gir + ghr);
    float z  = sigf(giz + ghz);
    float nn = tanhf_(gin + r * ghn);
    float hn = z * (hown - nn) + nn;
    bool conv = (!own) || (fabsf(hn - hown) <= DEPS);
    if (own) {
      orow[t * FEAT + j] = hn;           // lanes 0-12: contiguous 52B
      hown = hn;
    }
    if (__all(conv)) {  // converged within eps -> tail is ~constant
      if (own) hsh[j] = hown;
      asm volatile("s_waitcnt lgkmcnt(0)" ::: "memory");
      const int total = TSTEPS * FEAT;
      int idx = (t + 1) * FEAT + j;
      if (idx < total) {
        int jj = idx % FEAT;             // one div at entry
        for (; idx < total; idx += 64) {
          orow[idx] = hsh[jj];           // 64x4B coalesced per iteration
          jj = (jj == 0) ? (FEAT - 1) : (jj - 1);   // (jj+64) mod 13
        }
      }
      break;
    }
  }
}

extern "C" void kernel_launch(void* const* d_in, const int* in_sizes, int n_in,
                              void* d_out, int out_size, void* d_ws, size_t ws_size,
                              hipStream_t stream) {
  (void)in_sizes; (void)n_in; (void)out_size; (void)d_ws; (void)ws_size;
  const float* x    = (const float*)d_in[0];
  const float* eWih = (const float*)d_in[1];
  const float* eWhh = (const float*)d_in[2];
  const float* ebih = (const float*)d_in[3];
  const float* ebhh = (const float*)d_in[4];
  const float* fcW  = (const float*)d_in[5];
  const float* fcb  = (const float*)d_in[6];
  const float* dWih = (const float*)d_in[7];
  const float* dWhh = (const float*)d_in[8];
  const float* dbih = (const float*)d_in[9];
  const float* dbhh = (const float*)d_in[10];

  hipLaunchKernelGGL(gru_enc, dim3(BATCH / ROWS), dim3(1024), 0, stream,
                     x, eWih, eWhh, ebih, ebhh, fcW, fcb, (float*)d_out);
  hipLaunchKernelGGL(gru_dec, dim3(BATCH), dim3(64), 0, stream,
                     dWih, dWhh, dbih, dbhh, (float*)d_out);
}